// Round 1
// baseline (914.140 us; speedup 1.0000x reference)
//
#include <hip/hip_runtime.h>

// TSM variant: x shape (B=8, T=16, C=96, H=112, W=112) fp32.
//   c%3==0: out = (t<12) ? 0 : x[b,t,c]
//   c%3==1: out = (t<4)  ? 0 : x[b,t-4,c]
//   c%3==2: out = x
// Pure bandwidth kernel. One float4 per thread; each 64-lane wave sits
// entirely inside one (b,t,c) HW-plane (3136 float4 = 49 waves), so the
// per-channel branch is wave-uniform (no divergence).

namespace {
constexpr int kHW4    = (112 * 112) / 4;            // 3136 float4 per plane
constexpr int kC      = 96;
constexpr int kT      = 16;
constexpr int kB      = 8;
constexpr int kTotal4 = kB * kT * kC * kHW4;        // 38,535,168
constexpr int kShift4 = 4 * kC * kHW4;              // t -> t-4 offset in float4
}

__global__ __launch_bounds__(256) void tsm_shift_kernel(
    const float4* __restrict__ x, float4* __restrict__ out) {
  int i = blockIdx.x * blockDim.x + threadIdx.x;
  if (i >= kTotal4) return;

  int plane = i / kHW4;              // (b*T + t)*C + c   -- const-div -> magic mul
  int c = plane % kC;
  int t = (plane / kC) % kT;
  int r = c % 3;

  float4 v = make_float4(0.f, 0.f, 0.f, 0.f);
  if (r == 2) {
    v = x[i];
  } else if (r == 0) {
    if (t >= 12) v = x[i];
  } else {  // r == 1
    if (t >= 4) v = x[i - kShift4];
  }
  out[i] = v;
}

extern "C" void kernel_launch(void* const* d_in, const int* in_sizes, int n_in,
                              void* d_out, int out_size, void* d_ws, size_t ws_size,
                              hipStream_t stream) {
  const float4* x = (const float4*)d_in[0];
  float4* out = (float4*)d_out;
  const int threads = 256;
  const int blocks = (kTotal4 + threads - 1) / threads;  // 150,528
  tsm_shift_kernel<<<blocks, threads, 0, stream>>>(x, out);
}